// Round 6
// baseline (1331.929 us; speedup 1.0000x reference)
//
#include <hip/hip_runtime.h>
#include <cstdint>

// DynamicExpert: act = topk60(sigmoid(act @ synapse.T)), 2 steps.
// B=8, DIM=8192, fp32. W (256 MiB) is L3-resident in steady state; gemv is
// NOT HBM-bound (R4: 1.7 TB/s effective, FETCH 57 MB) — it was LDS-pipe +
// latency bound.
// R7: loop-swap gemv. R4 re-read the row-invariant A fragment from LDS for
//     every row (512 ds_read_b128/wave -> 41 us/CU of LDS service). Now
//     windows are outer, rows inner: A window ds_read ONCE per window and
//     reused by all 4 rows (ds cut 8x), W prefetched one window ahead
//     (R3's idea, now at ~115 VGPR instead of 200). ROWS_PER_WAVE=4,
//     __launch_bounds__(512,4) targets 4 waves/SIMD.
//     Per-acc chain order (win ascending, xyzw), shuffle tree, P0+P1+P2+P3
//     combine all preserved -> bit-identical to the absmax=0.0 baseline.

#define DIM 8192
#define BATCH 8
#define KSPLIT 4
#define KSPAN 2048           // DIM / KSPLIT
#define ROWS_PER_BLK 32
#define GEMV_THREADS 512     // 8 waves
#define ROWS_PER_WAVE 4      // ROWS_PER_BLK / 8 waves

__device__ __forceinline__ float sigmoidf_(float x) {
    return 1.0f / (1.0f + __expf(-x));
}

// Partial gemv: P[h][b][r] = sum_{j in h-span} A[b][j] * W[r][j].
// Block (h, rowgrp): stages A[8][KSPAN] (64 KB LDS) once. Each wave owns 4
// rows. Per 256-j window: prefetch next window's 4 W float4 (HBM/L3 stream
// stays in flight across the FMA burst), ds_read the 8 A float4 (shared by
// all rows), 128 FMAs. ds_read count is 8x lower than R4.
__global__ __launch_bounds__(GEMV_THREADS, 4) void gemv_part(
    const float* __restrict__ A,
    const float* __restrict__ W,
    float* __restrict__ P)
{
    __shared__ float As[BATCH * KSPAN];   // 64 KB exactly

    const int tid     = threadIdx.x;
    const int h       = blockIdx.x & 3;
    const int rowbase = (blockIdx.x >> 2) * ROWS_PER_BLK;
    const int kbeg    = h * KSPAN;

    // stage A[0..8)[kbeg..kbeg+KSPAN) -> As, float4-coalesced
    {
        const float4* Ag  = (const float4*)A;
        float4*       As4 = (float4*)As;
#pragma unroll
        for (int i = 0; i < 8; ++i) {
            const int q = tid + i * GEMV_THREADS;   // 0..4095
            const int b = q >> 9;                   // 512 float4 per A row span
            const int c = q & 511;
            As4[q] = Ag[b * (DIM / 4) + (kbeg >> 2) + c];
        }
    }
    __syncthreads();

    const int lane = tid & 63;
    const int wid  = tid >> 6;
    const int r0   = rowbase + wid * ROWS_PER_WAVE;

    const float* wr[ROWS_PER_WAVE];
#pragma unroll
    for (int r = 0; r < ROWS_PER_WAVE; ++r)
        wr[r] = W + (size_t)(r0 + r) * DIM + kbeg + lane * 4;

    float acc[ROWS_PER_WAVE][8];
#pragma unroll
    for (int r = 0; r < ROWS_PER_WAVE; ++r)
#pragma unroll
        for (int b = 0; b < 8; ++b) acc[r][b] = 0.0f;

    float4 wc[ROWS_PER_WAVE], wn[ROWS_PER_WAVE];
#pragma unroll
    for (int r = 0; r < ROWS_PER_WAVE; ++r)
        wc[r] = *(const float4*)(wr[r]);

#pragma unroll
    for (int win = 0; win < 8; ++win) {
        if (win < 7) {
#pragma unroll
            for (int r = 0; r < ROWS_PER_WAVE; ++r)
                wn[r] = *(const float4*)(wr[r] + (win + 1) * 256);
        }
        float4 a[8];
        {
            const float* abase = As + win * 256 + lane * 4;
#pragma unroll
            for (int b = 0; b < 8; ++b)
                a[b] = *(const float4*)(abase + b * KSPAN);
        }
#pragma unroll
        for (int r = 0; r < ROWS_PER_WAVE; ++r) {
#pragma unroll
            for (int b = 0; b < 8; ++b) {
                acc[r][b] += wc[r].x * a[b].x;
                acc[r][b] += wc[r].y * a[b].y;
                acc[r][b] += wc[r].z * a[b].z;
                acc[r][b] += wc[r].w * a[b].w;
            }
        }
#pragma unroll
        for (int r = 0; r < ROWS_PER_WAVE; ++r) wc[r] = wn[r];
    }

    // 64-lane tree, identical to R1
#pragma unroll
    for (int r = 0; r < ROWS_PER_WAVE; ++r) {
#pragma unroll
        for (int b = 0; b < 8; ++b) {
            float v = acc[r][b];
#pragma unroll
            for (int off = 32; off > 0; off >>= 1)
                v += __shfl_down(v, off, 64);
            if (lane == 0)
                P[((size_t)(h * BATCH + b)) * DIM + (r0 + r)] = v;
        }
    }
}

// ---- fused 4-partial reduce + sigmoid + top-k --------------------------
// v = sigmoid(((P0+P1)+P2)+P3)  (same combine order as R1's part[0..3]).
// Then radix top-k (3-level histogram) identical to R2/R3.

__device__ __forceinline__ void scan_small(const int* hist, int nb, int k_need,
                                           int lane, int* s_cut, int* s_gt)
{
    int running = 0;
    for (int cb = nb - 64; cb >= 0; cb -= 64) {
        const int b = cb + 63 - lane;          // lane 0 = highest bucket
        const int val = hist[b];
        int c = val;
#pragma unroll
        for (int o = 1; o < 64; o <<= 1) {
            const int u = __shfl_up(c, o, 64);
            if (lane >= o) c += u;
        }
        const unsigned long long m = __ballot(running + c >= k_need);
        if (m) {
            const int f = (int)__ffsll(m) - 1;
            const int cf = __shfl(c, f, 64);
            const int vf = __shfl(val, f, 64);
            if (lane == 0) { *s_cut = cb + 63 - f; *s_gt = running + cf - vf; }
            return;
        }
        running += __shfl(c, 63, 64);
    }
    if (lane == 0) { *s_cut = 0; *s_gt = 0; }  // unreachable for valid k
}

__device__ __forceinline__ void scan_l1(const int* hist, const int* coarse,
                                        int k_need, int lane,
                                        int* s_cut, int* s_gt)
{
    int running = 0, seg = -1, segGT = 0;
    for (int cb = 192; cb >= 0 && seg < 0; cb -= 64) {
        const int b = cb + 63 - lane;
        const int val = coarse[b];
        int c = val;
#pragma unroll
        for (int o = 1; o < 64; o <<= 1) {
            const int u = __shfl_up(c, o, 64);
            if (lane >= o) c += u;
        }
        const unsigned long long m = __ballot(running + c >= k_need);
        if (m) {
            const int f = (int)__ffsll(m) - 1;
            seg = cb + 63 - f;
            segGT = running + __shfl(c, f, 64) - __shfl(val, f, 64);
        } else {
            running += __shfl(c, 63, 64);
        }
    }
    if (seg < 0) seg = 0;                      // defensive; valid k never hits
    const int b = seg * 32 + 31 - lane;
    const int val = (lane < 32) ? hist[b] : 0;
    int c = val;
#pragma unroll
    for (int o = 1; o < 64; o <<= 1) {
        const int u = __shfl_up(c, o, 64);
        if (lane >= o) c += u;
    }
    const unsigned long long m = __ballot(segGT + c >= k_need);
    const int f = (int)__ffsll(m) - 1;         // crossing is within lanes 0..31
    const int cf = __shfl(c, f, 64);
    const int vf = __shfl(val, f, 64);
    if (lane == 0) { *s_cut = seg * 32 + 31 - f; *s_gt = segGT + cf - vf; }
}

__global__ __launch_bounds__(256) void topk_fused(
    const float* __restrict__ P,        // [KSPLIT][BATCH][DIM] partials
    float* __restrict__ Yout,           // [BATCH][DIM] dense output
    const int* __restrict__ kptr)
{
    const int row  = blockIdx.x;        // batch index b
    const int tid  = threadIdx.x;
    const int lane = tid & 63;
    const int wid  = tid >> 6;
    int k = kptr ? *kptr : 60;
    if (k > DIM) k = DIM;

    // reduce partials (R1's part[0]+part[1]+part[2]+part[3] order) + sigmoid
    uint32_t v[32];
    const float* Pb = P + (size_t)row * DIM;
#pragma unroll
    for (int i = 0; i < 32; ++i) {
        const int idx = tid + i * 256;
        float s = Pb[idx];
        s += Pb[idx + 1 * BATCH * DIM];
        s += Pb[idx + 2 * BATCH * DIM];
        s += Pb[idx + 3 * BATCH * DIM];
        v[i] = __float_as_uint(sigmoidf_(s));
    }

    float* dst = Yout + (size_t)row * DIM;
    if (k <= 0) {
#pragma unroll
        for (int i = 0; i < 32; ++i) dst[tid + i * 256] = 0.0f;
        return;
    }

    __shared__ int hist[8192];     // 32 KB
    __shared__ int coarse[256];
    __shared__ int s_cut, s_gt, s_ctr;

    // ---- level 1: bits >> 17 ----
    for (int i = tid; i < 8192; i += 256) hist[i] = 0;
    __syncthreads();
#pragma unroll
    for (int i = 0; i < 32; ++i) atomicAdd(&hist[v[i] >> 17], 1);
    __syncthreads();
    {
        int s = 0;
        const int base = tid * 32;
        for (int i = 0; i < 32; ++i) s += hist[base + i];
        coarse[tid] = s;
    }
    __syncthreads();
    if (wid == 0) scan_l1(hist, coarse, k, lane, &s_cut, &s_gt);
    __syncthreads();
    const uint32_t cut1 = (uint32_t)s_cut;
    const int gt1 = s_gt;

    // ---- level 2: (bits >> 8) & 0x1FF ----
    for (int i = tid; i < 512; i += 256) hist[i] = 0;
    __syncthreads();
#pragma unroll
    for (int i = 0; i < 32; ++i)
        if ((v[i] >> 17) == cut1) atomicAdd(&hist[(v[i] >> 8) & 0x1FF], 1);
    __syncthreads();
    if (wid == 0) scan_small(hist, 512, k - gt1, lane, &s_cut, &s_gt);
    __syncthreads();
    const uint32_t cut2 = (uint32_t)s_cut;
    const int gt2 = s_gt;

    // ---- level 3: bits & 0xFF ----
    const uint32_t pref = (cut1 << 9) | cut2;
    for (int i = tid; i < 256; i += 256) hist[i] = 0;
    if (tid == 0) s_ctr = 0;
    __syncthreads();
#pragma unroll
    for (int i = 0; i < 32; ++i)
        if ((v[i] >> 8) == pref) atomicAdd(&hist[v[i] & 0xFF], 1);
    __syncthreads();
    if (wid == 0) scan_small(hist, 256, k - gt1 - gt2, lane, &s_cut, &s_gt);
    __syncthreads();
    const uint32_t cut3 = (uint32_t)s_cut;
    const int gt3 = s_gt;

    const uint32_t cutoff  = (pref << 8) | cut3;   // k-th largest value's bits
    const int      need_eq = k - (gt1 + gt2 + gt3);

#pragma unroll
    for (int i = 0; i < 32; ++i) {
        const uint32_t b = v[i];
        float val = 0.0f;
        if (b > cutoff) {
            val = __uint_as_float(b);
        } else if (b == cutoff) {
            const int pos = atomicAdd(&s_ctr, 1);
            if (pos < need_eq) val = __uint_as_float(b);
        }
        dst[tid + i * 256] = val;
    }
}

extern "C" void kernel_launch(void* const* d_in, const int* in_sizes, int n_in,
                              void* d_out, int out_size, void* d_ws, size_t ws_size,
                              hipStream_t stream) {
    const float* sdr = (const float*)d_in[0];
    const float* syn = (const float*)d_in[1];
    const int* kptr  = (n_in > 3) ? (const int*)d_in[3] : nullptr;
    float* out = (float*)d_out;
    float* P   = (float*)d_ws;            // KSPLIT*8*8192 floats = 1 MB

    const int nblk = KSPLIT * (DIM / ROWS_PER_BLK);   // 1024

    // step 1: partials = sdr @ W^T (K-split), fused reduce+sigmoid+topk -> out
    gemv_part<<<nblk, GEMV_THREADS, 0, stream>>>(sdr, syn, P);
    topk_fused<<<8, 256, 0, stream>>>(P, out, kptr);
    // step 2: same with act1 as A
    gemv_part<<<nblk, GEMV_THREADS, 0, stream>>>(out, syn, P);
    topk_fused<<<8, 256, 0, stream>>>(P, out, kptr);
}

// Round 7
// 886.943 us; speedup vs baseline: 1.5017x; 1.5017x over previous
//
#include <hip/hip_runtime.h>
#include <cstdint>

// DynamicExpert: act = topk60(sigmoid(act @ synapse.T)), 2 steps.
// B=8, DIM=8192, fp32. W (256 MiB) is L2/L3-resident in steady state
// (R4: FETCH 57 MB) — gemv is issue/latency-bound, not HBM-bound.
// R8 = R7 with the spill bug fixed. R7's __launch_bounds__(512,4) made the
//     compiler cap at 64 VGPR (8 waves/SIMD target) and spill ~570 MB of
//     scratch per dispatch (WRITE_SIZE tripwire). Plain (512) gave R4
//     128 VGPR, no spill; the loop-swapped kernel needs ~115.
// R7 structure: windows outer, rows inner — the row-invariant A window is
//     ds_read ONCE per window and reused by 4 rows (8x fewer ds_reads than
//     R4's 160 us kernel), W prefetched one window ahead. Per-acc chain
//     order, shuffle tree, P0+P1+P2+P3 combine preserved -> bit-identical.

#define DIM 8192
#define BATCH 8
#define KSPLIT 4
#define KSPAN 2048           // DIM / KSPLIT
#define ROWS_PER_BLK 32
#define GEMV_THREADS 512     // 8 waves
#define ROWS_PER_WAVE 4      // ROWS_PER_BLK / 8 waves

__device__ __forceinline__ float sigmoidf_(float x) {
    return 1.0f / (1.0f + __expf(-x));
}

// Partial gemv: P[h][b][r] = sum_{j in h-span} A[b][j] * W[r][j].
// Block (h, rowgrp): stages A[8][KSPAN] (64 KB LDS) once. Each wave owns 4
// rows. Per 256-j window: prefetch next window's 4 W float4 (L3 stream
// stays in flight across the FMA burst), ds_read the 8 A float4 (shared by
// all rows), 128 FMAs.
__global__ __launch_bounds__(GEMV_THREADS) void gemv_part(
    const float* __restrict__ A,
    const float* __restrict__ W,
    float* __restrict__ P)
{
    __shared__ float As[BATCH * KSPAN];   // 64 KB exactly

    const int tid     = threadIdx.x;
    const int h       = blockIdx.x & 3;
    const int rowbase = (blockIdx.x >> 2) * ROWS_PER_BLK;
    const int kbeg    = h * KSPAN;

    // stage A[0..8)[kbeg..kbeg+KSPAN) -> As, float4-coalesced
    {
        const float4* Ag  = (const float4*)A;
        float4*       As4 = (float4*)As;
#pragma unroll
        for (int i = 0; i < 8; ++i) {
            const int q = tid + i * GEMV_THREADS;   // 0..4095
            const int b = q >> 9;                   // 512 float4 per A row span
            const int c = q & 511;
            As4[q] = Ag[b * (DIM / 4) + (kbeg >> 2) + c];
        }
    }
    __syncthreads();

    const int lane = tid & 63;
    const int wid  = tid >> 6;
    const int r0   = rowbase + wid * ROWS_PER_WAVE;

    const float* wr[ROWS_PER_WAVE];
#pragma unroll
    for (int r = 0; r < ROWS_PER_WAVE; ++r)
        wr[r] = W + (size_t)(r0 + r) * DIM + kbeg + lane * 4;

    float acc[ROWS_PER_WAVE][8];
#pragma unroll
    for (int r = 0; r < ROWS_PER_WAVE; ++r)
#pragma unroll
        for (int b = 0; b < 8; ++b) acc[r][b] = 0.0f;

    float4 wc[ROWS_PER_WAVE], wn[ROWS_PER_WAVE];
#pragma unroll
    for (int r = 0; r < ROWS_PER_WAVE; ++r)
        wc[r] = *(const float4*)(wr[r]);

#pragma unroll
    for (int win = 0; win < 8; ++win) {
        if (win < 7) {
#pragma unroll
            for (int r = 0; r < ROWS_PER_WAVE; ++r)
                wn[r] = *(const float4*)(wr[r] + (win + 1) * 256);
        }
        float4 a[8];
        {
            const float* abase = As + win * 256 + lane * 4;
#pragma unroll
            for (int b = 0; b < 8; ++b)
                a[b] = *(const float4*)(abase + b * KSPAN);
        }
#pragma unroll
        for (int r = 0; r < ROWS_PER_WAVE; ++r) {
#pragma unroll
            for (int b = 0; b < 8; ++b) {
                acc[r][b] += wc[r].x * a[b].x;
                acc[r][b] += wc[r].y * a[b].y;
                acc[r][b] += wc[r].z * a[b].z;
                acc[r][b] += wc[r].w * a[b].w;
            }
        }
#pragma unroll
        for (int r = 0; r < ROWS_PER_WAVE; ++r) wc[r] = wn[r];
    }

    // 64-lane tree, identical to R1
#pragma unroll
    for (int r = 0; r < ROWS_PER_WAVE; ++r) {
#pragma unroll
        for (int b = 0; b < 8; ++b) {
            float v = acc[r][b];
#pragma unroll
            for (int off = 32; off > 0; off >>= 1)
                v += __shfl_down(v, off, 64);
            if (lane == 0)
                P[((size_t)(h * BATCH + b)) * DIM + (r0 + r)] = v;
        }
    }
}

// ---- fused 4-partial reduce + sigmoid + top-k --------------------------
// v = sigmoid(((P0+P1)+P2)+P3)  (same combine order as R1's part[0..3]).
// Then radix top-k (3-level histogram) identical to R2/R3.

__device__ __forceinline__ void scan_small(const int* hist, int nb, int k_need,
                                           int lane, int* s_cut, int* s_gt)
{
    int running = 0;
    for (int cb = nb - 64; cb >= 0; cb -= 64) {
        const int b = cb + 63 - lane;          // lane 0 = highest bucket
        const int val = hist[b];
        int c = val;
#pragma unroll
        for (int o = 1; o < 64; o <<= 1) {
            const int u = __shfl_up(c, o, 64);
            if (lane >= o) c += u;
        }
        const unsigned long long m = __ballot(running + c >= k_need);
        if (m) {
            const int f = (int)__ffsll(m) - 1;
            const int cf = __shfl(c, f, 64);
            const int vf = __shfl(val, f, 64);
            if (lane == 0) { *s_cut = cb + 63 - f; *s_gt = running + cf - vf; }
            return;
        }
        running += __shfl(c, 63, 64);
    }
    if (lane == 0) { *s_cut = 0; *s_gt = 0; }  // unreachable for valid k
}

__device__ __forceinline__ void scan_l1(const int* hist, const int* coarse,
                                        int k_need, int lane,
                                        int* s_cut, int* s_gt)
{
    int running = 0, seg = -1, segGT = 0;
    for (int cb = 192; cb >= 0 && seg < 0; cb -= 64) {
        const int b = cb + 63 - lane;
        const int val = coarse[b];
        int c = val;
#pragma unroll
        for (int o = 1; o < 64; o <<= 1) {
            const int u = __shfl_up(c, o, 64);
            if (lane >= o) c += u;
        }
        const unsigned long long m = __ballot(running + c >= k_need);
        if (m) {
            const int f = (int)__ffsll(m) - 1;
            seg = cb + 63 - f;
            segGT = running + __shfl(c, f, 64) - __shfl(val, f, 64);
        } else {
            running += __shfl(c, 63, 64);
        }
    }
    if (seg < 0) seg = 0;                      // defensive; valid k never hits
    const int b = seg * 32 + 31 - lane;
    const int val = (lane < 32) ? hist[b] : 0;
    int c = val;
#pragma unroll
    for (int o = 1; o < 64; o <<= 1) {
        const int u = __shfl_up(c, o, 64);
        if (lane >= o) c += u;
    }
    const unsigned long long m = __ballot(segGT + c >= k_need);
    const int f = (int)__ffsll(m) - 1;         // crossing is within lanes 0..31
    const int cf = __shfl(c, f, 64);
    const int vf = __shfl(val, f, 64);
    if (lane == 0) { *s_cut = seg * 32 + 31 - f; *s_gt = segGT + cf - vf; }
}

__global__ __launch_bounds__(256) void topk_fused(
    const float* __restrict__ P,        // [KSPLIT][BATCH][DIM] partials
    float* __restrict__ Yout,           // [BATCH][DIM] dense output
    const int* __restrict__ kptr)
{
    const int row  = blockIdx.x;        // batch index b
    const int tid  = threadIdx.x;
    const int lane = tid & 63;
    const int wid  = tid >> 6;
    int k = kptr ? *kptr : 60;
    if (k > DIM) k = DIM;

    // reduce partials (R1's part[0]+part[1]+part[2]+part[3] order) + sigmoid
    uint32_t v[32];
    const float* Pb = P + (size_t)row * DIM;
#pragma unroll
    for (int i = 0; i < 32; ++i) {
        const int idx = tid + i * 256;
        float s = Pb[idx];
        s += Pb[idx + 1 * BATCH * DIM];
        s += Pb[idx + 2 * BATCH * DIM];
        s += Pb[idx + 3 * BATCH * DIM];
        v[i] = __float_as_uint(sigmoidf_(s));
    }

    float* dst = Yout + (size_t)row * DIM;
    if (k <= 0) {
#pragma unroll
        for (int i = 0; i < 32; ++i) dst[tid + i * 256] = 0.0f;
        return;
    }

    __shared__ int hist[8192];     // 32 KB
    __shared__ int coarse[256];
    __shared__ int s_cut, s_gt, s_ctr;

    // ---- level 1: bits >> 17 ----
    for (int i = tid; i < 8192; i += 256) hist[i] = 0;
    __syncthreads();
#pragma unroll
    for (int i = 0; i < 32; ++i) atomicAdd(&hist[v[i] >> 17], 1);
    __syncthreads();
    {
        int s = 0;
        const int base = tid * 32;
        for (int i = 0; i < 32; ++i) s += hist[base + i];
        coarse[tid] = s;
    }
    __syncthreads();
    if (wid == 0) scan_l1(hist, coarse, k, lane, &s_cut, &s_gt);
    __syncthreads();
    const uint32_t cut1 = (uint32_t)s_cut;
    const int gt1 = s_gt;

    // ---- level 2: (bits >> 8) & 0x1FF ----
    for (int i = tid; i < 512; i += 256) hist[i] = 0;
    __syncthreads();
#pragma unroll
    for (int i = 0; i < 32; ++i)
        if ((v[i] >> 17) == cut1) atomicAdd(&hist[(v[i] >> 8) & 0x1FF], 1);
    __syncthreads();
    if (wid == 0) scan_small(hist, 512, k - gt1, lane, &s_cut, &s_gt);
    __syncthreads();
    const uint32_t cut2 = (uint32_t)s_cut;
    const int gt2 = s_gt;

    // ---- level 3: bits & 0xFF ----
    const uint32_t pref = (cut1 << 9) | cut2;
    for (int i = tid; i < 256; i += 256) hist[i] = 0;
    if (tid == 0) s_ctr = 0;
    __syncthreads();
#pragma unroll
    for (int i = 0; i < 32; ++i)
        if ((v[i] >> 8) == pref) atomicAdd(&hist[v[i] & 0xFF], 1);
    __syncthreads();
    if (wid == 0) scan_small(hist, 256, k - gt1 - gt2, lane, &s_cut, &s_gt);
    __syncthreads();
    const uint32_t cut3 = (uint32_t)s_cut;
    const int gt3 = s_gt;

    const uint32_t cutoff  = (pref << 8) | cut3;   // k-th largest value's bits
    const int      need_eq = k - (gt1 + gt2 + gt3);

#pragma unroll
    for (int i = 0; i < 32; ++i) {
        const uint32_t b = v[i];
        float val = 0.0f;
        if (b > cutoff) {
            val = __uint_as_float(b);
        } else if (b == cutoff) {
            const int pos = atomicAdd(&s_ctr, 1);
            if (pos < need_eq) val = __uint_as_float(b);
        }
        dst[tid + i * 256] = val;
    }
}

extern "C" void kernel_launch(void* const* d_in, const int* in_sizes, int n_in,
                              void* d_out, int out_size, void* d_ws, size_t ws_size,
                              hipStream_t stream) {
    const float* sdr = (const float*)d_in[0];
    const float* syn = (const float*)d_in[1];
    const int* kptr  = (n_in > 3) ? (const int*)d_in[3] : nullptr;
    float* out = (float*)d_out;
    float* P   = (float*)d_ws;            // KSPLIT*8*8192 floats = 1 MB

    const int nblk = KSPLIT * (DIM / ROWS_PER_BLK);   // 1024

    // step 1: partials = sdr @ W^T (K-split), fused reduce+sigmoid+topk -> out
    gemv_part<<<nblk, GEMV_THREADS, 0, stream>>>(sdr, syn, P);
    topk_fused<<<8, 256, 0, stream>>>(P, out, kptr);
    // step 2: same with act1 as A
    gemv_part<<<nblk, GEMV_THREADS, 0, stream>>>(out, syn, P);
    topk_fused<<<8, 256, 0, stream>>>(P, out, kptr);
}